// Round 9
// baseline (827.688 us; speedup 1.0000x reference)
//
#include <hip/hip_runtime.h>
#include <hip/hip_bf16.h>
#include <cstdint>

// ---------------------------------------------------------------------------
// MolGraphEncoder r9: fused layers with hoisted bounds/self-loads (deep gather
// pipeline), direct-fp32 layer-0 kernel (k_xd eliminated), merged scan.
// ---------------------------------------------------------------------------

typedef __attribute__((ext_vector_type(8))) short short8;
typedef __attribute__((ext_vector_type(4))) float f32x4;

__device__ __forceinline__ float b2f(unsigned int hi16) {
    return __builtin_bit_cast(float, hi16);
}
__device__ __forceinline__ unsigned short f2b(float f) {  // RTN-even
    unsigned int u = __builtin_bit_cast(unsigned int, f);
    u += 0x7fffu + ((u >> 16) & 1u);
    return (unsigned short)(u >> 16);
}
__device__ __forceinline__ unsigned int packbf(float lo, float hi) {
    return ((unsigned int)f2b(hi) << 16) | f2b(lo);
}

__global__ void k_count(const int* __restrict__ dst, int* __restrict__ cnt, int E) {
    int e = blockIdx.x * blockDim.x + threadIdx.x;
    if (e < E) atomicAdd(&cnt[dst[e]], 1);
}

// --- scan (2048/block) + fused dis = rsqrt(deg+1) ---------------------------
__global__ void k_scan1(const int* __restrict__ in, int* __restrict__ out1,
                        int* __restrict__ bsum, float* __restrict__ dis, int n) {
    __shared__ int s[256];
    int t = threadIdx.x;
    int base = blockIdx.x * 2048 + t * 8;
    int v[8];
    int run = 0;
#pragma unroll
    for (int i = 0; i < 8; ++i) {
        int idx = base + i;
        int x = (idx < n) ? in[idx] : 0;
        if (idx < n) dis[idx] = rsqrtf((float)x + 1.0f);
        run += x;
        v[i] = run;
    }
    s[t] = run;
    __syncthreads();
    for (int off = 1; off < 256; off <<= 1) {
        int add = (t >= off) ? s[t - off] : 0;
        __syncthreads();
        s[t] += add;
        __syncthreads();
    }
    int pre = (t > 0) ? s[t - 1] : 0;
#pragma unroll
    for (int i = 0; i < 8; ++i) {
        int idx = base + i;
        if (idx < n) out1[idx] = v[i] + pre;
    }
    if (t == 255) bsum[blockIdx.x] = s[255];
}

// scan3 with internal bsum-prefix reduction (replaces scan2+scan3)
__global__ void k_scan3(int* __restrict__ rowstart, const int* __restrict__ bsum, int n) {
    int b = blockIdx.x, t = threadIdx.x;
    if (b == 0) {
        if (t == 0) rowstart[0] = 0;
        return;
    }
    __shared__ int ws[4];
    int v = (t < b) ? bsum[t] : 0;  // nb <= 256 guaranteed by launch config
#pragma unroll
    for (int off = 32; off; off >>= 1) v += __shfl_xor(v, off);
    if ((t & 63) == 0) ws[t >> 6] = v;
    __syncthreads();
    int add = ws[0] + ws[1] + ws[2] + ws[3];
    int* out1 = rowstart + 1;
    int base = b * 2048 + t * 8;
#pragma unroll
    for (int i = 0; i < 8; ++i) {
        int idx = base + i;
        if (idx < n) out1[idx] += add;
    }
}

// fill CSR: position = rowstart[d] + zero-based atomic offset
__global__ void k_fill(const int* __restrict__ src, const int* __restrict__ dst,
                       const int* __restrict__ rowstart, int* __restrict__ cur0,
                       int* __restrict__ csr_src, int E) {
    int e = blockIdx.x * blockDim.x + threadIdx.x;
    if (e >= E) return;
    int d = dst[e];
    int pos = rowstart[d] + atomicAdd(&cur0[d], 1);
    csr_src[pos] = src[e];
}

// --- pack all 3 weights into MFMA B-fragment layout (bf16, K padded) --------
__global__ void k_cvtw3(const float* __restrict__ W0, const float* __restrict__ W1,
                        const float* __restrict__ W2, unsigned short* __restrict__ wp0,
                        unsigned short* __restrict__ wp1, unsigned short* __restrict__ wp2) {
    int tid = blockIdx.x * blockDim.x + threadIdx.x;
    const float* W;
    unsigned short* o;
    int Ksrc, f;
    if (tid < 3 * 512) { W = W0; o = wp0; Ksrc = 82; f = tid; }
    else if (tid < 7 * 512) { W = W1; o = wp1; Ksrc = 128; f = tid - 3 * 512; }
    else if (tid < 11 * 512) { W = W2; o = wp2; Ksrc = 128; f = tid - 7 * 512; }
    else return;
    int lane = f & 63, fr = f >> 6;
    int m = fr >> 3, ct = fr & 7;
    int col = ct * 16 + (lane & 15);
    int kb = m * 32 + ((lane >> 4) << 3);
    unsigned short v[8];
#pragma unroll
    for (int j = 0; j < 8; ++j) {
        int k = kb + j;
        v[j] = (k < Ksrc) ? f2b(W[k * 128 + col]) : (unsigned short)0;
    }
    *(short8*)(o + (size_t)f * 8) = *(short8*)v;
}

// --- layer 0: direct fp32-x gather -> swizzled LDS -> MFMA (K=96) -----------
__global__ __launch_bounds__(256, 6) void k_fused0(
    const float* __restrict__ x, const float* __restrict__ dis,
    const int* __restrict__ rowstart, const int* __restrict__ csr,
    const unsigned short* __restrict__ Wp, const float* __restrict__ bias,
    unsigned short* __restrict__ out, int n) {
    __shared__ unsigned int As[64 * 64];
    int t = threadIdx.x, lane = t & 63, w = t >> 6;
    int tile = blockIdx.x * 64;
    const bool act = lane < 41;  // cols 2*lane, 2*lane+1 <= 81
    const int c0 = (act ? lane : 0) * 2;
    int sbase = tile + (w << 4);

    int bb[17];
#pragma unroll
    for (int i = 0; i < 17; ++i) {
        int idx = sbase + i;
        bb[i] = rowstart[idx < n ? idx : n];
    }

#pragma unroll
    for (int g = 0; g < 4; ++g) {
        int r = (w << 4) + g * 4;
        int v0 = tile + r;
        unsigned int* dst0 = &As[(r + 0) * 64 + (lane ^ (((r + 0) & 7) << 2))];
        unsigned int* dst1 = &As[(r + 1) * 64 + (lane ^ (((r + 1) & 7) << 2))];
        unsigned int* dst2 = &As[(r + 2) * 64 + (lane ^ (((r + 2) & 7) << 2))];
        unsigned int* dst3 = &As[(r + 3) * 64 + (lane ^ (((r + 3) & 7) << 2))];
        int nv = n - v0;
        nv = nv < 0 ? 0 : (nv > 4 ? 4 : nv);
        if (nv == 0) {
            *dst0 = 0u; *dst1 = 0u; *dst2 = 0u; *dst3 = 0u;
            continue;
        }
        int e0 = bb[g * 4], b1 = bb[g * 4 + 1], b2 = bb[g * 4 + 2],
            b3 = bb[g * 4 + 3], eE = bb[g * 4 + 4];
        int vc1 = (nv > 1) ? v0 + 1 : v0;
        int vc2 = (nv > 2) ? v0 + 2 : v0;
        int vc3 = (nv > 3) ? v0 + 3 : v0;
        float2 t0 = *(const float2*)(x + (size_t)v0 * 82 + c0);
        float2 t1 = *(const float2*)(x + (size_t)vc1 * 82 + c0);
        float2 t2 = *(const float2*)(x + (size_t)vc2 * 82 + c0);
        float2 t3 = *(const float2*)(x + (size_t)vc3 * 82 + c0);
        float d0 = dis[v0], d1 = dis[vc1], d2 = dis[vc2], d3 = dis[vc3];
        float a0x = d0 * t0.x, a0y = d0 * t0.y;
        float a1x = d1 * t1.x, a1y = d1 * t1.y;
        float a2x = d2 * t2.x, a2y = d2 * t2.y;
        float a3x = d3 * t3.x, a3y = d3 * t3.y;

        for (int e = e0; e < eE; e += 8) {
            int rem = eE - e;
            int i1 = (rem > 1) ? e + 1 : e;
            int i2 = (rem > 2) ? e + 2 : e;
            int i3 = (rem > 3) ? e + 3 : e;
            int i4 = (rem > 4) ? e + 4 : e;
            int i5 = (rem > 5) ? e + 5 : e;
            int i6 = (rem > 6) ? e + 6 : e;
            int i7 = (rem > 7) ? e + 7 : e;
            int u0 = csr[e],  u1 = csr[i1], u2 = csr[i2], u3 = csr[i3];
            int u4 = csr[i4], u5 = csr[i5], u6 = csr[i6], u7 = csr[i7];
            float2 r0 = *(const float2*)(x + (size_t)u0 * 82 + c0);
            float2 r1 = *(const float2*)(x + (size_t)u1 * 82 + c0);
            float2 r2 = *(const float2*)(x + (size_t)u2 * 82 + c0);
            float2 r3 = *(const float2*)(x + (size_t)u3 * 82 + c0);
            float2 r4 = *(const float2*)(x + (size_t)u4 * 82 + c0);
            float2 r5 = *(const float2*)(x + (size_t)u5 * 82 + c0);
            float2 r6 = *(const float2*)(x + (size_t)u6 * 82 + c0);
            float2 r7 = *(const float2*)(x + (size_t)u7 * 82 + c0);
            float du0 = dis[u0], du1 = dis[u1], du2 = dis[u2], du3 = dis[u3];
            float du4 = dis[u4], du5 = dis[u5], du6 = dis[u6], du7 = dis[u7];
#define ACC0(DU, RV, ei)                                                  \
            {                                                             \
                if ((ei) < b1) { a0x = fmaf(DU, RV.x, a0x); a0y = fmaf(DU, RV.y, a0y); } \
                else if ((ei) < b2) { a1x = fmaf(DU, RV.x, a1x); a1y = fmaf(DU, RV.y, a1y); } \
                else if ((ei) < b3) { a2x = fmaf(DU, RV.x, a2x); a2y = fmaf(DU, RV.y, a2y); } \
                else { a3x = fmaf(DU, RV.x, a3x); a3y = fmaf(DU, RV.y, a3y); } \
            }
            ACC0(du0, r0, e)
            if (rem > 1) ACC0(du1, r1, e + 1)
            if (rem > 2) ACC0(du2, r2, e + 2)
            if (rem > 3) ACC0(du3, r3, e + 3)
            if (rem > 4) ACC0(du4, r4, e + 4)
            if (rem > 5) ACC0(du5, r5, e + 5)
            if (rem > 6) ACC0(du6, r6, e + 6)
            if (rem > 7) ACC0(du7, r7, e + 7)
#undef ACC0
        }
        *dst0 = act ? packbf(d0 * a0x, d0 * a0y) : 0u;
        *dst1 = (act && nv > 1) ? packbf(d1 * a1x, d1 * a1y) : 0u;
        *dst2 = (act && nv > 2) ? packbf(d2 * a2x, d2 * a2y) : 0u;
        *dst3 = (act && nv > 3) ? packbf(d3 * a3x, d3 * a3y) : 0u;
    }
    __syncthreads();

    // ---- phase 2: KS=3 MFMA strip ----
    int r0i = lane & 15, ch = lane >> 4;
    const unsigned int* arow = &As[((w << 4) + r0i) << 6];
    f32x4 acc[8];
#pragma unroll
    for (int ct = 0; ct < 8; ++ct) acc[ct] = (f32x4){0.f, 0.f, 0.f, 0.f};
#pragma unroll
    for (int m = 0; m < 3; ++m) {
        int slot = (ch + 4 * m) ^ (r0i & 7);
        short8 a = *(const short8*)(arow + slot * 4);
        const short8* wf = (const short8*)Wp + ((size_t)(m * 8) * 64 + lane);
#pragma unroll
        for (int ct = 0; ct < 8; ++ct) {
            short8 b = wf[ct * 64];
            acc[ct] = __builtin_amdgcn_mfma_f32_16x16x32_bf16(a, b, acc[ct], 0, 0, 0);
        }
    }

    float bbv[8];
#pragma unroll
    for (int ct = 0; ct < 8; ++ct) bbv[ct] = bias[ct * 16 + r0i];
    int rbase = tile + (w << 4) + (ch << 2);
#pragma unroll
    for (int reg = 0; reg < 4; ++reg) {
        int row = rbase + reg;
        bool ok = row < n;
        float dv = ok ? dis[row] : 1.f;
#pragma unroll
        for (int ct = 0; ct < 8; ++ct) {
            float o = fmaxf(acc[ct][reg] + bbv[ct], 0.f);
            if (ok) out[(size_t)row * 128 + ct * 16 + r0i] = f2b(o * dv);
        }
    }
}

// --- bf16 fused layer (K=128): hoisted bounds+selfs, 8-deep gather, MFMA ----
template <bool SCALE, bool GATE>
__global__ __launch_bounds__(256, 8) void k_fused(
    const unsigned int* __restrict__ hd, const float* __restrict__ dis,
    const int* __restrict__ rowstart, const int* __restrict__ csr,
    const unsigned short* __restrict__ Wp, const float* __restrict__ bias,
    unsigned short* __restrict__ out, const float* __restrict__ gw,
    const float* __restrict__ gb, float* __restrict__ gate, int n) {
    __shared__ unsigned int As[64 * 64];
    int t = threadIdx.x, lane = t & 63, w = t >> 6;
    int tile = blockIdx.x * 64;
    int sbase = tile + (w << 4);

    int bb[17];
#pragma unroll
    for (int i = 0; i < 17; ++i) {
        int idx = sbase + i;
        bb[i] = rowstart[idx < n ? idx : n];
    }
    unsigned int selfv[16];
#pragma unroll
    for (int i = 0; i < 16; ++i) {
        int v = sbase + i;
        int vc = (v < n) ? v : 0;
        unsigned int val = hd[(size_t)vc * 64 + lane];
        selfv[i] = (v < n) ? val : 0u;
    }

#pragma unroll
    for (int g = 0; g < 4; ++g) {
        int r = (w << 4) + g * 4;
        int v0 = tile + r;
        unsigned int* dst0 = &As[(r + 0) * 64 + (lane ^ (((r + 0) & 7) << 2))];
        unsigned int* dst1 = &As[(r + 1) * 64 + (lane ^ (((r + 1) & 7) << 2))];
        unsigned int* dst2 = &As[(r + 2) * 64 + (lane ^ (((r + 2) & 7) << 2))];
        unsigned int* dst3 = &As[(r + 3) * 64 + (lane ^ (((r + 3) & 7) << 2))];
        int nv = n - v0;
        nv = nv < 0 ? 0 : (nv > 4 ? 4 : nv);
        int e0 = bb[g * 4], b1 = bb[g * 4 + 1], b2 = bb[g * 4 + 2],
            b3 = bb[g * 4 + 3], eE = bb[g * 4 + 4];
        float a0x = b2f(selfv[g * 4 + 0] << 16), a0y = b2f(selfv[g * 4 + 0] & 0xffff0000u);
        float a1x = b2f(selfv[g * 4 + 1] << 16), a1y = b2f(selfv[g * 4 + 1] & 0xffff0000u);
        float a2x = b2f(selfv[g * 4 + 2] << 16), a2y = b2f(selfv[g * 4 + 2] & 0xffff0000u);
        float a3x = b2f(selfv[g * 4 + 3] << 16), a3y = b2f(selfv[g * 4 + 3] & 0xffff0000u);

        for (int e = e0; e < eE; e += 8) {
            int rem = eE - e;
            int i1 = (rem > 1) ? e + 1 : e;
            int i2 = (rem > 2) ? e + 2 : e;
            int i3 = (rem > 3) ? e + 3 : e;
            int i4 = (rem > 4) ? e + 4 : e;
            int i5 = (rem > 5) ? e + 5 : e;
            int i6 = (rem > 6) ? e + 6 : e;
            int i7 = (rem > 7) ? e + 7 : e;
            int u0 = csr[e],  u1 = csr[i1], u2 = csr[i2], u3 = csr[i3];
            int u4 = csr[i4], u5 = csr[i5], u6 = csr[i6], u7 = csr[i7];
            unsigned int r0v = hd[(size_t)u0 * 64 + lane];
            unsigned int r1v = hd[(size_t)u1 * 64 + lane];
            unsigned int r2v = hd[(size_t)u2 * 64 + lane];
            unsigned int r3v = hd[(size_t)u3 * 64 + lane];
            unsigned int r4v = hd[(size_t)u4 * 64 + lane];
            unsigned int r5v = hd[(size_t)u5 * 64 + lane];
            unsigned int r6v = hd[(size_t)u6 * 64 + lane];
            unsigned int r7v = hd[(size_t)u7 * 64 + lane];
#define ACC(rv, ei)                                                     \
            {                                                           \
                float fx = b2f((rv) << 16), fy = b2f((rv) & 0xffff0000u); \
                if ((ei) < b1) { a0x += fx; a0y += fy; }                \
                else if ((ei) < b2) { a1x += fx; a1y += fy; }           \
                else if ((ei) < b3) { a2x += fx; a2y += fy; }           \
                else { a3x += fx; a3y += fy; }                          \
            }
            ACC(r0v, e)
            if (rem > 1) ACC(r1v, e + 1)
            if (rem > 2) ACC(r2v, e + 2)
            if (rem > 3) ACC(r3v, e + 3)
            if (rem > 4) ACC(r4v, e + 4)
            if (rem > 5) ACC(r5v, e + 5)
            if (rem > 6) ACC(r6v, e + 6)
            if (rem > 7) ACC(r7v, e + 7)
#undef ACC
        }

        int vc1 = (nv > 1) ? v0 + 1 : 0;
        int vc2 = (nv > 2) ? v0 + 2 : 0;
        int vc3 = (nv > 3) ? v0 + 3 : 0;
        float d0 = dis[(nv > 0) ? v0 : 0];
        float d1 = dis[vc1], d2 = dis[vc2], d3 = dis[vc3];
        *dst0 = (nv > 0) ? packbf(d0 * a0x, d0 * a0y) : 0u;
        *dst1 = (nv > 1) ? packbf(d1 * a1x, d1 * a1y) : 0u;
        *dst2 = (nv > 2) ? packbf(d2 * a2x, d2 * a2y) : 0u;
        *dst3 = (nv > 3) ? packbf(d3 * a3x, d3 * a3y) : 0u;
    }
    __syncthreads();

    // ---- phase 2: KS=4 MFMA strip ----
    int r0i = lane & 15, ch = lane >> 4;
    const unsigned int* arow = &As[((w << 4) + r0i) << 6];
    f32x4 acc[8];
#pragma unroll
    for (int ct = 0; ct < 8; ++ct) acc[ct] = (f32x4){0.f, 0.f, 0.f, 0.f};
#pragma unroll
    for (int m = 0; m < 4; ++m) {
        int slot = (ch + 4 * m) ^ (r0i & 7);
        short8 a = *(const short8*)(arow + slot * 4);
        const short8* wf = (const short8*)Wp + ((size_t)(m * 8) * 64 + lane);
#pragma unroll
        for (int ct = 0; ct < 8; ++ct) {
            short8 b = wf[ct * 64];
            acc[ct] = __builtin_amdgcn_mfma_f32_16x16x32_bf16(a, b, acc[ct], 0, 0, 0);
        }
    }

    // ---- epilogue ----
    float bbv[8], gwv[8];
#pragma unroll
    for (int ct = 0; ct < 8; ++ct) {
        bbv[ct] = bias[ct * 16 + r0i];
        if (GATE) gwv[ct] = gw[ct * 16 + r0i];
    }
    float gbv = GATE ? gb[0] : 0.f;
    int rbase = tile + (w << 4) + (ch << 2);
#pragma unroll
    for (int reg = 0; reg < 4; ++reg) {
        int row = rbase + reg;
        bool ok = row < n;
        float dv = (SCALE && ok) ? dis[row] : 1.f;
        float gp = 0.f;
#pragma unroll
        for (int ct = 0; ct < 8; ++ct) {
            float o = fmaxf(acc[ct][reg] + bbv[ct], 0.f);
            if (GATE) gp = fmaf(o, gwv[ct], gp);
            if (ok) out[(size_t)row * 128 + ct * 16 + r0i] = f2b(SCALE ? o * dv : o);
        }
        if (GATE) {
            gp += __shfl_xor(gp, 1);
            gp += __shfl_xor(gp, 2);
            gp += __shfl_xor(gp, 4);
            gp += __shfl_xor(gp, 8);
            if (r0i == 0 && ok) gate[row] = gp + gbv;
        }
    }
}

// --- attention pooling: one wave per graph, inline boundary search ----------
__global__ __launch_bounds__(256) void k_pool(const unsigned short* __restrict__ h,
                                              const float* __restrict__ gate,
                                              const int* __restrict__ batch,
                                              float* __restrict__ emb, int n, int B) {
    int wid = (blockIdx.x * blockDim.x + threadIdx.x) >> 6;
    int lane = threadIdx.x & 63;
    if (wid >= B) return;
    int bnd = 0;
    if (lane < 2) {
        int g = wid + lane;
        int lo = 0, hi = n;
        while (lo < hi) {
            int mid = (lo + hi) >> 1;
            if (batch[mid] < g) lo = mid + 1;
            else hi = mid;
        }
        bnd = lo;
    }
    int s = __shfl(bnd, 0), e2 = __shfl(bnd, 1);
    float* ev2 = emb + (size_t)wid * 128 + lane * 2;
    if (s >= e2) {
        ev2[0] = 0.f;
        ev2[1] = 0.f;
        return;
    }
    float m = -INFINITY;
    for (int v = s + lane; v < e2; v += 64) m = fmaxf(m, gate[v]);
#pragma unroll
    for (int off = 32; off; off >>= 1) m = fmaxf(m, __shfl_xor(m, off));
    float a0 = 0.f, a1 = 0.f, den = 0.f;
    for (int v = s; v < e2; ++v) {
        float ev = __expf(gate[v] - m);
        den += ev;
        unsigned int hv = *(const unsigned int*)((const char*)h + (size_t)v * 256 + lane * 4);
        a0 = fmaf(ev, b2f(hv << 16), a0);
        a1 = fmaf(ev, b2f(hv & 0xffff0000u), a1);
    }
    float inv = 1.f / den;
    ev2[0] = a0 * inv;
    ev2[1] = a1 * inv;
}

// --- final projection: 32 graphs per block ----------------------------------
__global__ __launch_bounds__(256) void k_proj(const float* __restrict__ emb,
                                              const float* __restrict__ pw,
                                              const float* __restrict__ pb,
                                              float* __restrict__ out, int B) {
    __shared__ float es[32][128];
    int g0 = blockIdx.x * 32;
    int t = threadIdx.x;
    for (int i = t; i < 1024; i += 256) {
        int g = g0 + (i >> 5);
        float4 val = (g < B) ? ((const float4*)emb)[(size_t)g * 32 + (i & 31)]
                             : make_float4(0.f, 0.f, 0.f, 0.f);
        *(float4*)&es[i >> 5][(i & 31) * 4] = val;
    }
    __syncthreads();
    float acc[32];
#pragma unroll
    for (int i = 0; i < 32; ++i) acc[i] = 0.f;
    for (int k = 0; k < 128; ++k) {
        float wv = pw[k * 256 + t];
#pragma unroll
        for (int i = 0; i < 32; ++i) acc[i] = fmaf(es[i][k], wv, acc[i]);
    }
    float b = pb[t];
#pragma unroll
    for (int i = 0; i < 32; ++i) {
        int g = g0 + i;
        if (g < B) out[(size_t)g * 256 + t] = acc[i] + b;
    }
}

// ---------------------------------------------------------------------------
extern "C" void kernel_launch(void* const* d_in, const int* in_sizes, int n_in,
                              void* d_out, int out_size, void* d_ws, size_t ws_size,
                              hipStream_t stream) {
    const float* x = (const float*)d_in[0];
    const int* ei = (const int*)d_in[1];
    const int* batch = (const int*)d_in[2];
    const float* W0 = (const float*)d_in[3];
    const float* b0 = (const float*)d_in[4];
    const float* W1 = (const float*)d_in[5];
    const float* b1 = (const float*)d_in[6];
    const float* W2 = (const float*)d_in[7];
    const float* b2 = (const float*)d_in[8];
    const float* gw = (const float*)d_in[9];
    const float* gb = (const float*)d_in[10];
    const float* pw = (const float*)d_in[11];
    const float* pb = (const float*)d_in[12];
    float* out = (float*)d_out;

    const int N = in_sizes[2];
    const int E = in_sizes[1] / 2;
    const int B = out_size / 256;
    (void)n_in;

    const int* esrc = ei;
    const int* edst = ei + E;

    char* p = (char*)d_ws;
    auto carve = [&](size_t bytes) {
        char* r = p;
        p += (bytes + 255) & ~(size_t)255;
        return r;
    };
    unsigned int* hA = (unsigned int*)carve((size_t)N * 64 * 4);
    unsigned int* hB = (unsigned int*)carve((size_t)N * 64 * 4);
    float* emb = (float*)carve((size_t)B * 128 * 4);
    int* csr_src = (int*)carve((size_t)E * 4);
    float* dis = (float*)carve((size_t)N * 4);
    int* cnt = (int*)carve((size_t)2 * N * 4);  // cnt + cur0 (one memset)
    int* cur0 = cnt + N;
    int* rowstart = (int*)carve((size_t)(N + 1) * 4);
    float* gate = (float*)carve((size_t)N * 4);
    int* bsum = (int*)carve((size_t)4096 * 4);
    unsigned short* wp0 = (unsigned short*)carve((size_t)3 * 512 * 8 * 2);
    unsigned short* wp1 = (unsigned short*)carve((size_t)4 * 512 * 8 * 2);
    unsigned short* wp2 = (unsigned short*)carve((size_t)4 * 512 * 8 * 2);
    if ((size_t)(p - (char*)d_ws) > ws_size) return;

    const int nb = (N + 2047) / 2048;  // 245 (<= 256 required by k_scan3)

    hipMemsetAsync(cnt, 0, (size_t)2 * N * 4, stream);
    k_count<<<(E + 255) / 256, 256, 0, stream>>>(edst, cnt, E);
    k_scan1<<<nb, 256, 0, stream>>>(cnt, rowstart + 1, bsum, dis, N);
    k_scan3<<<nb, 256, 0, stream>>>(rowstart, bsum, N);
    k_fill<<<(E + 255) / 256, 256, 0, stream>>>(esrc, edst, rowstart, cur0, csr_src, E);
    k_cvtw3<<<22, 256, 0, stream>>>(W0, W1, W2, wp0, wp1, wp2);

    const int fb = (N + 63) / 64;

    // layer 0: x (fp32) -> hA (bf16 pair-packed, dis-prescaled)
    k_fused0<<<fb, 256, 0, stream>>>(x, dis, rowstart, csr_src, wp0, b0,
                                     (unsigned short*)hA, N);
    // layer 1: hA -> hB (dis-prescaled)
    k_fused<true, false><<<fb, 256, 0, stream>>>(
        hA, dis, rowstart, csr_src, wp1, b1, (unsigned short*)hB,
        nullptr, nullptr, nullptr, N);
    // layer 2: hB -> hA (unscaled) + gate
    k_fused<false, true><<<fb, 256, 0, stream>>>(
        hB, dis, rowstart, csr_src, wp2, b2, (unsigned short*)hA,
        gw, gb, gate, N);

    // pooling + projection
    k_pool<<<(B + 3) / 4, 256, 0, stream>>>((const unsigned short*)hA, gate, batch,
                                            emb, N, B);
    k_proj<<<(B + 31) / 32, 256, 0, stream>>>(emb, pw, pb, out, B);
}

// Round 10
// 622.357 us; speedup vs baseline: 1.3299x; 1.3299x over previous
//
#include <hip/hip_runtime.h>
#include <hip/hip_bf16.h>
#include <cstdint>

// ---------------------------------------------------------------------------
// MolGraphEncoder r10: r8 structure with single-wave (64-thread) fused-layer
// blocks (no barrier, wave-private 16-row LDS tile), merged scan, ILP-4 pool.
// ---------------------------------------------------------------------------

typedef __attribute__((ext_vector_type(8))) short short8;
typedef __attribute__((ext_vector_type(4))) float f32x4;

__device__ __forceinline__ float b2f(unsigned int hi16) {
    return __builtin_bit_cast(float, hi16);
}
__device__ __forceinline__ unsigned short f2b(float f) {  // RTN-even
    unsigned int u = __builtin_bit_cast(unsigned int, f);
    u += 0x7fffu + ((u >> 16) & 1u);
    return (unsigned short)(u >> 16);
}
__device__ __forceinline__ unsigned int packbf(float lo, float hi) {
    return ((unsigned int)f2b(hi) << 16) | f2b(lo);
}

__global__ void k_count(const int* __restrict__ dst, int* __restrict__ cnt, int E) {
    int e = blockIdx.x * blockDim.x + threadIdx.x;
    if (e < E) atomicAdd(&cnt[dst[e]], 1);
}

// --- scan (2048/block) + fused dis = rsqrt(deg+1) ---------------------------
__global__ void k_scan1(const int* __restrict__ in, int* __restrict__ out1,
                        int* __restrict__ bsum, float* __restrict__ dis, int n) {
    __shared__ int s[256];
    int t = threadIdx.x;
    int base = blockIdx.x * 2048 + t * 8;
    int v[8];
    int run = 0;
#pragma unroll
    for (int i = 0; i < 8; ++i) {
        int idx = base + i;
        int x = (idx < n) ? in[idx] : 0;
        if (idx < n) dis[idx] = rsqrtf((float)x + 1.0f);
        run += x;
        v[i] = run;
    }
    s[t] = run;
    __syncthreads();
    for (int off = 1; off < 256; off <<= 1) {
        int add = (t >= off) ? s[t - off] : 0;
        __syncthreads();
        s[t] += add;
        __syncthreads();
    }
    int pre = (t > 0) ? s[t - 1] : 0;
#pragma unroll
    for (int i = 0; i < 8; ++i) {
        int idx = base + i;
        if (idx < n) out1[idx] = v[i] + pre;
    }
    if (t == 255) bsum[blockIdx.x] = s[255];
}

// scan3 with internal bsum-prefix reduction (replaces scan2+scan3)
__global__ void k_scan3(int* __restrict__ rowstart, const int* __restrict__ bsum, int n) {
    int b = blockIdx.x, t = threadIdx.x;
    if (b == 0) {
        if (t == 0) rowstart[0] = 0;
        return;
    }
    __shared__ int ws[4];
    int v = (t < b) ? bsum[t] : 0;  // nb <= 256 guaranteed by launch config
#pragma unroll
    for (int off = 32; off; off >>= 1) v += __shfl_xor(v, off);
    if ((t & 63) == 0) ws[t >> 6] = v;
    __syncthreads();
    int add = ws[0] + ws[1] + ws[2] + ws[3];
    int* out1 = rowstart + 1;
    int base = b * 2048 + t * 8;
#pragma unroll
    for (int i = 0; i < 8; ++i) {
        int idx = base + i;
        if (idx < n) out1[idx] += add;
    }
}

// fill CSR: position = rowstart[d] + zero-based atomic offset
__global__ void k_fill(const int* __restrict__ src, const int* __restrict__ dst,
                       const int* __restrict__ rowstart, int* __restrict__ cur0,
                       int* __restrict__ csr_src, int E) {
    int e = blockIdx.x * blockDim.x + threadIdx.x;
    if (e >= E) return;
    int d = dst[e];
    int pos = rowstart[d] + atomicAdd(&cur0[d], 1);
    csr_src[pos] = src[e];
}

// --- pack all 3 weights into MFMA B-fragment layout (bf16, K padded) --------
__global__ void k_cvtw3(const float* __restrict__ W0, const float* __restrict__ W1,
                        const float* __restrict__ W2, unsigned short* __restrict__ wp0,
                        unsigned short* __restrict__ wp1, unsigned short* __restrict__ wp2) {
    int tid = blockIdx.x * blockDim.x + threadIdx.x;
    const float* W;
    unsigned short* o;
    int Ksrc, f;
    if (tid < 3 * 512) { W = W0; o = wp0; Ksrc = 82; f = tid; }
    else if (tid < 7 * 512) { W = W1; o = wp1; Ksrc = 128; f = tid - 3 * 512; }
    else if (tid < 11 * 512) { W = W2; o = wp2; Ksrc = 128; f = tid - 7 * 512; }
    else return;
    int lane = f & 63, fr = f >> 6;
    int m = fr >> 3, ct = fr & 7;
    int col = ct * 16 + (lane & 15);
    int kb = m * 32 + ((lane >> 4) << 3);
    unsigned short v[8];
#pragma unroll
    for (int j = 0; j < 8; ++j) {
        int k = kb + j;
        v[j] = (k < Ksrc) ? f2b(W[k * 128 + col]) : (unsigned short)0;
    }
    *(short8*)(o + (size_t)f * 8) = *(short8*)v;
}

// --- xd = bf16(dis[v] * x[v]), 82 cols padded to 96 (48 u32/row) ------------
__global__ __launch_bounds__(256) void k_xd(const float* __restrict__ x,
                                            const float* __restrict__ dis,
                                            unsigned int* __restrict__ xd, int n) {
    int tid = blockIdx.x * blockDim.x + threadIdx.x;
    if (tid >= n * 48) return;
    int v = tid / 48;
    int c = (tid - v * 48) * 2;
    float dv = dis[v];
    const float* xv = x + (size_t)v * 82;
    float fx = (c < 82) ? dv * xv[c] : 0.f;
    float fy = (c + 1 < 82) ? dv * xv[c + 1] : 0.f;
    xd[tid] = packbf(fx, fy);
}

// --- fused GCN layer, single-wave block (16 rows, no barrier) ---------------
// Input rows: RU = KS*16 u32 (2 bf16 each), dis-prescaled by producer.
// agg[v] = dis[v] * ( in[v] + sum_{u->v} in[u] );  out = relu(agg @ W + b)
// SCALE: out *= dis[row] (pre-scale for next layer). GATE: fused gate dot.
template <int KS, bool SCALE, bool GATE>
__global__ __launch_bounds__(64, 8) void k_fused(
    const unsigned int* __restrict__ hd, const float* __restrict__ dis,
    const int* __restrict__ rowstart, const int* __restrict__ csr,
    const unsigned short* __restrict__ Wp, const float* __restrict__ bias,
    unsigned short* __restrict__ out, const float* __restrict__ gw,
    const float* __restrict__ gb, float* __restrict__ gate, int n) {
    constexpr int RU = KS * 16;  // u32 per input row
    __shared__ unsigned int As[16 * 64];  // 16 rows x 256B (zero-padded), swizzled
    int lane = threadIdx.x & 63;
    int tile = blockIdx.x * 16;
    const bool act = (RU == 64) ? true : (lane < RU);
    const int li = act ? lane : 0;

    // ---- phase 1: gather 16 rows as 4 buckets of 4 (8-edge ILP) ----
    for (int g = 0; g < 4; ++g) {
        int r = g * 4;
        int v0 = tile + r;
        unsigned int* dst0 = &As[(r + 0) * 64 + (lane ^ (((r + 0) & 7) << 2))];
        unsigned int* dst1 = &As[(r + 1) * 64 + (lane ^ (((r + 1) & 7) << 2))];
        unsigned int* dst2 = &As[(r + 2) * 64 + (lane ^ (((r + 2) & 7) << 2))];
        unsigned int* dst3 = &As[(r + 3) * 64 + (lane ^ (((r + 3) & 7) << 2))];
        if (v0 >= n) {
            *dst0 = 0u; *dst1 = 0u; *dst2 = 0u; *dst3 = 0u;
            continue;
        }
        int nv = n - v0;
        if (nv > 4) nv = 4;
        int e0 = rowstart[v0];
        int eE = rowstart[v0 + nv];
        int b1 = (nv > 1) ? rowstart[v0 + 1] : eE;
        int b2 = (nv > 2) ? rowstart[v0 + 2] : eE;
        int b3 = (nv > 3) ? rowstart[v0 + 3] : eE;

        unsigned int s0 = hd[(size_t)v0 * RU + li];
        unsigned int s1 = (nv > 1) ? hd[(size_t)(v0 + 1) * RU + li] : 0u;
        unsigned int s2 = (nv > 2) ? hd[(size_t)(v0 + 2) * RU + li] : 0u;
        unsigned int s3 = (nv > 3) ? hd[(size_t)(v0 + 3) * RU + li] : 0u;
        float a0x = b2f(s0 << 16), a0y = b2f(s0 & 0xffff0000u);
        float a1x = b2f(s1 << 16), a1y = b2f(s1 & 0xffff0000u);
        float a2x = b2f(s2 << 16), a2y = b2f(s2 & 0xffff0000u);
        float a3x = b2f(s3 << 16), a3y = b2f(s3 & 0xffff0000u);

        for (int e = e0; e < eE; e += 8) {
            int rem = eE - e;
            int i1 = (rem > 1) ? e + 1 : e;
            int i2 = (rem > 2) ? e + 2 : e;
            int i3 = (rem > 3) ? e + 3 : e;
            int i4 = (rem > 4) ? e + 4 : e;
            int i5 = (rem > 5) ? e + 5 : e;
            int i6 = (rem > 6) ? e + 6 : e;
            int i7 = (rem > 7) ? e + 7 : e;
            int u0 = csr[e],  u1 = csr[i1], u2 = csr[i2], u3 = csr[i3];
            int u4 = csr[i4], u5 = csr[i5], u6 = csr[i6], u7 = csr[i7];
            unsigned int r0v = hd[(size_t)u0 * RU + li];
            unsigned int r1v = hd[(size_t)u1 * RU + li];
            unsigned int r2v = hd[(size_t)u2 * RU + li];
            unsigned int r3v = hd[(size_t)u3 * RU + li];
            unsigned int r4v = hd[(size_t)u4 * RU + li];
            unsigned int r5v = hd[(size_t)u5 * RU + li];
            unsigned int r6v = hd[(size_t)u6 * RU + li];
            unsigned int r7v = hd[(size_t)u7 * RU + li];
#define ACC(rv, ei)                                                     \
            {                                                           \
                float fx = b2f((rv) << 16), fy = b2f((rv) & 0xffff0000u); \
                if ((ei) < b1) { a0x += fx; a0y += fy; }                \
                else if ((ei) < b2) { a1x += fx; a1y += fy; }           \
                else if ((ei) < b3) { a2x += fx; a2y += fy; }           \
                else { a3x += fx; a3y += fy; }                          \
            }
            ACC(r0v, e)
            if (rem > 1) ACC(r1v, e + 1)
            if (rem > 2) ACC(r2v, e + 2)
            if (rem > 3) ACC(r3v, e + 3)
            if (rem > 4) ACC(r4v, e + 4)
            if (rem > 5) ACC(r5v, e + 5)
            if (rem > 6) ACC(r6v, e + 6)
            if (rem > 7) ACC(r7v, e + 7)
#undef ACC
        }

        float d0 = dis[v0];
        float d1 = (nv > 1) ? dis[v0 + 1] : 0.f;
        float d2 = (nv > 2) ? dis[v0 + 2] : 0.f;
        float d3 = (nv > 3) ? dis[v0 + 3] : 0.f;
        *dst0 = act ? packbf(d0 * a0x, d0 * a0y) : 0u;
        *dst1 = (act && nv > 1) ? packbf(d1 * a1x, d1 * a1y) : 0u;
        *dst2 = (act && nv > 2) ? packbf(d2 * a2x, d2 * a2y) : 0u;
        *dst3 = (act && nv > 3) ? packbf(d3 * a3x, d3 * a3y) : 0u;
    }
    // single wave: LDS writes visible after s_waitcnt; no barrier needed

    // ---- phase 2: MFMA on the 16-row tile ----
    int r0 = lane & 15, ch = lane >> 4;
    const unsigned int* arow = &As[r0 << 6];
    f32x4 acc[8];
#pragma unroll
    for (int ct = 0; ct < 8; ++ct) acc[ct] = (f32x4){0.f, 0.f, 0.f, 0.f};
#pragma unroll
    for (int m = 0; m < KS; ++m) {
        int slot = (ch + 4 * m) ^ (r0 & 7);
        short8 a = *(const short8*)(arow + slot * 4);
        const short8* wf = (const short8*)Wp + ((size_t)(m * 8) * 64 + lane);
#pragma unroll
        for (int ct = 0; ct < 8; ++ct) {
            short8 b = wf[ct * 64];
            acc[ct] = __builtin_amdgcn_mfma_f32_16x16x32_bf16(a, b, acc[ct], 0, 0, 0);
        }
    }

    // ---- epilogue ----
    float bb[8], gwv[8];
#pragma unroll
    for (int ct = 0; ct < 8; ++ct) {
        bb[ct] = bias[ct * 16 + r0];
        if (GATE) gwv[ct] = gw[ct * 16 + r0];
    }
    float gbv = GATE ? gb[0] : 0.f;
    int rbase = tile + (ch << 2);
#pragma unroll
    for (int reg = 0; reg < 4; ++reg) {
        int row = rbase + reg;
        bool ok = row < n;
        float dv = (SCALE && ok) ? dis[row] : 1.f;
        float gp = 0.f;
#pragma unroll
        for (int ct = 0; ct < 8; ++ct) {
            float o = fmaxf(acc[ct][reg] + bb[ct], 0.f);
            if (GATE) gp = fmaf(o, gwv[ct], gp);
            if (ok) out[(size_t)row * 128 + ct * 16 + r0] = f2b(SCALE ? o * dv : o);
        }
        if (GATE) {
            gp += __shfl_xor(gp, 1);
            gp += __shfl_xor(gp, 2);
            gp += __shfl_xor(gp, 4);
            gp += __shfl_xor(gp, 8);
            if (r0 == 0 && ok) gate[row] = gp + gbv;
        }
    }
}

// --- attention pooling: one wave per graph, inline bounds, ILP-4 sum --------
__global__ __launch_bounds__(256) void k_pool(const unsigned short* __restrict__ h,
                                              const float* __restrict__ gate,
                                              const int* __restrict__ batch,
                                              float* __restrict__ emb, int n, int B) {
    int wid = (blockIdx.x * blockDim.x + threadIdx.x) >> 6;
    int lane = threadIdx.x & 63;
    if (wid >= B) return;
    int bnd = 0;
    if (lane < 2) {
        int g = wid + lane;
        int lo = 0, hi = n;
        while (lo < hi) {
            int mid = (lo + hi) >> 1;
            if (batch[mid] < g) lo = mid + 1;
            else hi = mid;
        }
        bnd = lo;
    }
    int s = __shfl(bnd, 0), e2 = __shfl(bnd, 1);
    float* ev2 = emb + (size_t)wid * 128 + lane * 2;
    if (s >= e2) {
        ev2[0] = 0.f;
        ev2[1] = 0.f;
        return;
    }
    float m = -INFINITY;
    for (int v = s + lane; v < e2; v += 64) m = fmaxf(m, gate[v]);
#pragma unroll
    for (int off = 32; off; off >>= 1) m = fmaxf(m, __shfl_xor(m, off));
    float a0 = 0.f, a1 = 0.f, den = 0.f;
    const unsigned int* h32 = (const unsigned int*)h;
    int v = s;
    for (; v + 4 <= e2; v += 4) {
        float g0 = gate[v], g1 = gate[v + 1], g2 = gate[v + 2], g3 = gate[v + 3];
        unsigned int h0 = h32[(size_t)(v + 0) * 64 + lane];
        unsigned int h1 = h32[(size_t)(v + 1) * 64 + lane];
        unsigned int h2 = h32[(size_t)(v + 2) * 64 + lane];
        unsigned int h3 = h32[(size_t)(v + 3) * 64 + lane];
        float e0 = __expf(g0 - m), e1 = __expf(g1 - m);
        float e2v = __expf(g2 - m), e3 = __expf(g3 - m);
        den += (e0 + e1) + (e2v + e3);
        a0 = fmaf(e0, b2f(h0 << 16), a0);
        a1 = fmaf(e0, b2f(h0 & 0xffff0000u), a1);
        a0 = fmaf(e1, b2f(h1 << 16), a0);
        a1 = fmaf(e1, b2f(h1 & 0xffff0000u), a1);
        a0 = fmaf(e2v, b2f(h2 << 16), a0);
        a1 = fmaf(e2v, b2f(h2 & 0xffff0000u), a1);
        a0 = fmaf(e3, b2f(h3 << 16), a0);
        a1 = fmaf(e3, b2f(h3 & 0xffff0000u), a1);
    }
    for (; v < e2; ++v) {
        float ev = __expf(gate[v] - m);
        den += ev;
        unsigned int hv = h32[(size_t)v * 64 + lane];
        a0 = fmaf(ev, b2f(hv << 16), a0);
        a1 = fmaf(ev, b2f(hv & 0xffff0000u), a1);
    }
    float inv = 1.f / den;
    ev2[0] = a0 * inv;
    ev2[1] = a1 * inv;
}

// --- final projection: 32 graphs per block ----------------------------------
__global__ __launch_bounds__(256) void k_proj(const float* __restrict__ emb,
                                              const float* __restrict__ pw,
                                              const float* __restrict__ pb,
                                              float* __restrict__ out, int B) {
    __shared__ float es[32][128];
    int g0 = blockIdx.x * 32;
    int t = threadIdx.x;
    for (int i = t; i < 1024; i += 256) {
        int g = g0 + (i >> 5);
        float4 val = (g < B) ? ((const float4*)emb)[(size_t)g * 32 + (i & 31)]
                             : make_float4(0.f, 0.f, 0.f, 0.f);
        *(float4*)&es[i >> 5][(i & 31) * 4] = val;
    }
    __syncthreads();
    float acc[32];
#pragma unroll
    for (int i = 0; i < 32; ++i) acc[i] = 0.f;
    for (int k = 0; k < 128; ++k) {
        float wv = pw[k * 256 + t];
#pragma unroll
        for (int i = 0; i < 32; ++i) acc[i] = fmaf(es[i][k], wv, acc[i]);
    }
    float b = pb[t];
#pragma unroll
    for (int i = 0; i < 32; ++i) {
        int g = g0 + i;
        if (g < B) out[(size_t)g * 256 + t] = acc[i] + b;
    }
}

// ---------------------------------------------------------------------------
extern "C" void kernel_launch(void* const* d_in, const int* in_sizes, int n_in,
                              void* d_out, int out_size, void* d_ws, size_t ws_size,
                              hipStream_t stream) {
    const float* x = (const float*)d_in[0];
    const int* ei = (const int*)d_in[1];
    const int* batch = (const int*)d_in[2];
    const float* W0 = (const float*)d_in[3];
    const float* b0 = (const float*)d_in[4];
    const float* W1 = (const float*)d_in[5];
    const float* b1 = (const float*)d_in[6];
    const float* W2 = (const float*)d_in[7];
    const float* b2 = (const float*)d_in[8];
    const float* gw = (const float*)d_in[9];
    const float* gb = (const float*)d_in[10];
    const float* pw = (const float*)d_in[11];
    const float* pb = (const float*)d_in[12];
    float* out = (float*)d_out;

    const int N = in_sizes[2];
    const int E = in_sizes[1] / 2;
    const int B = out_size / 256;
    (void)n_in;

    const int* esrc = ei;
    const int* edst = ei + E;

    char* p = (char*)d_ws;
    auto carve = [&](size_t bytes) {
        char* r = p;
        p += (bytes + 255) & ~(size_t)255;
        return r;
    };
    unsigned int* xd = (unsigned int*)carve((size_t)N * 48 * 4);
    unsigned int* hA = (unsigned int*)carve((size_t)N * 64 * 4);
    unsigned int* hB = (unsigned int*)carve((size_t)N * 64 * 4);
    float* emb = (float*)carve((size_t)B * 128 * 4);
    int* csr_src = (int*)carve((size_t)E * 4);
    float* dis = (float*)carve((size_t)N * 4);
    int* cnt = (int*)carve((size_t)2 * N * 4);  // cnt + cur0 (one memset)
    int* cur0 = cnt + N;
    int* rowstart = (int*)carve((size_t)(N + 1) * 4);
    float* gate = (float*)carve((size_t)N * 4);
    int* bsum = (int*)carve((size_t)4096 * 4);
    unsigned short* wp0 = (unsigned short*)carve((size_t)3 * 512 * 8 * 2);
    unsigned short* wp1 = (unsigned short*)carve((size_t)4 * 512 * 8 * 2);
    unsigned short* wp2 = (unsigned short*)carve((size_t)4 * 512 * 8 * 2);
    if ((size_t)(p - (char*)d_ws) > ws_size) return;

    const int nb = (N + 2047) / 2048;  // 245 (<= 256 required by k_scan3)

    hipMemsetAsync(cnt, 0, (size_t)2 * N * 4, stream);
    k_count<<<(E + 255) / 256, 256, 0, stream>>>(edst, cnt, E);
    k_scan1<<<nb, 256, 0, stream>>>(cnt, rowstart + 1, bsum, dis, N);
    k_scan3<<<nb, 256, 0, stream>>>(rowstart, bsum, N);
    k_fill<<<(E + 255) / 256, 256, 0, stream>>>(esrc, edst, rowstart, cur0, csr_src, E);
    k_cvtw3<<<22, 256, 0, stream>>>(W0, W1, W2, wp0, wp1, wp2);
    k_xd<<<(N * 48 + 255) / 256, 256, 0, stream>>>(x, dis, xd, N);

    const int fb = (N + 15) / 16;  // single-wave blocks, 16 rows each

    // layer 0: xd -> hA (bf16, dis-prescaled)
    k_fused<3, true, false><<<fb, 64, 0, stream>>>(
        xd, dis, rowstart, csr_src, wp0, b0, (unsigned short*)hA,
        nullptr, nullptr, nullptr, N);
    // layer 1: hA -> hB (bf16, dis-prescaled)
    k_fused<4, true, false><<<fb, 64, 0, stream>>>(
        hA, dis, rowstart, csr_src, wp1, b1, (unsigned short*)hB,
        nullptr, nullptr, nullptr, N);
    // layer 2: hB -> hA (unscaled) + gate
    k_fused<4, false, true><<<fb, 64, 0, stream>>>(
        hB, dis, rowstart, csr_src, wp2, b2, (unsigned short*)hA,
        gw, gb, gate, N);

    // pooling + projection
    k_pool<<<(B + 3) / 4, 256, 0, stream>>>((const unsigned short*)hA, gate, batch,
                                            emb, N, B);
    k_proj<<<(B + 31) / 32, 256, 0, stream>>>(emb, pw, pb, out, B);
}

// Round 11
// 571.648 us; speedup vs baseline: 1.4479x; 1.0887x over previous
//
#include <hip/hip_runtime.h>
#include <hip/hip_bf16.h>
#include <cstdint>

// ---------------------------------------------------------------------------
// MolGraphEncoder r11: r10 (single-wave fused layers, merged scan, ILP pool)
// with 4x-vectorized k_xd (uint4 stores, 4 float2 loads in flight per thread).
// ---------------------------------------------------------------------------

typedef __attribute__((ext_vector_type(8))) short short8;
typedef __attribute__((ext_vector_type(4))) float f32x4;

__device__ __forceinline__ float b2f(unsigned int hi16) {
    return __builtin_bit_cast(float, hi16);
}
__device__ __forceinline__ unsigned short f2b(float f) {  // RTN-even
    unsigned int u = __builtin_bit_cast(unsigned int, f);
    u += 0x7fffu + ((u >> 16) & 1u);
    return (unsigned short)(u >> 16);
}
__device__ __forceinline__ unsigned int packbf(float lo, float hi) {
    return ((unsigned int)f2b(hi) << 16) | f2b(lo);
}

__global__ void k_count(const int* __restrict__ dst, int* __restrict__ cnt, int E) {
    int e = blockIdx.x * blockDim.x + threadIdx.x;
    if (e < E) atomicAdd(&cnt[dst[e]], 1);
}

// --- scan (2048/block) + fused dis = rsqrt(deg+1) ---------------------------
__global__ void k_scan1(const int* __restrict__ in, int* __restrict__ out1,
                        int* __restrict__ bsum, float* __restrict__ dis, int n) {
    __shared__ int s[256];
    int t = threadIdx.x;
    int base = blockIdx.x * 2048 + t * 8;
    int v[8];
    int run = 0;
#pragma unroll
    for (int i = 0; i < 8; ++i) {
        int idx = base + i;
        int x = (idx < n) ? in[idx] : 0;
        if (idx < n) dis[idx] = rsqrtf((float)x + 1.0f);
        run += x;
        v[i] = run;
    }
    s[t] = run;
    __syncthreads();
    for (int off = 1; off < 256; off <<= 1) {
        int add = (t >= off) ? s[t - off] : 0;
        __syncthreads();
        s[t] += add;
        __syncthreads();
    }
    int pre = (t > 0) ? s[t - 1] : 0;
#pragma unroll
    for (int i = 0; i < 8; ++i) {
        int idx = base + i;
        if (idx < n) out1[idx] = v[i] + pre;
    }
    if (t == 255) bsum[blockIdx.x] = s[255];
}

// scan3 with internal bsum-prefix reduction (replaces scan2+scan3)
__global__ void k_scan3(int* __restrict__ rowstart, const int* __restrict__ bsum, int n) {
    int b = blockIdx.x, t = threadIdx.x;
    if (b == 0) {
        if (t == 0) rowstart[0] = 0;
        return;
    }
    __shared__ int ws[4];
    int v = (t < b) ? bsum[t] : 0;  // nb <= 256 guaranteed by launch config
#pragma unroll
    for (int off = 32; off; off >>= 1) v += __shfl_xor(v, off);
    if ((t & 63) == 0) ws[t >> 6] = v;
    __syncthreads();
    int add = ws[0] + ws[1] + ws[2] + ws[3];
    int* out1 = rowstart + 1;
    int base = b * 2048 + t * 8;
#pragma unroll
    for (int i = 0; i < 8; ++i) {
        int idx = base + i;
        if (idx < n) out1[idx] += add;
    }
}

// fill CSR: position = rowstart[d] + zero-based atomic offset
__global__ void k_fill(const int* __restrict__ src, const int* __restrict__ dst,
                       const int* __restrict__ rowstart, int* __restrict__ cur0,
                       int* __restrict__ csr_src, int E) {
    int e = blockIdx.x * blockDim.x + threadIdx.x;
    if (e >= E) return;
    int d = dst[e];
    int pos = rowstart[d] + atomicAdd(&cur0[d], 1);
    csr_src[pos] = src[e];
}

// --- pack all 3 weights into MFMA B-fragment layout (bf16, K padded) --------
__global__ void k_cvtw3(const float* __restrict__ W0, const float* __restrict__ W1,
                        const float* __restrict__ W2, unsigned short* __restrict__ wp0,
                        unsigned short* __restrict__ wp1, unsigned short* __restrict__ wp2) {
    int tid = blockIdx.x * blockDim.x + threadIdx.x;
    const float* W;
    unsigned short* o;
    int Ksrc, f;
    if (tid < 3 * 512) { W = W0; o = wp0; Ksrc = 82; f = tid; }
    else if (tid < 7 * 512) { W = W1; o = wp1; Ksrc = 128; f = tid - 3 * 512; }
    else if (tid < 11 * 512) { W = W2; o = wp2; Ksrc = 128; f = tid - 7 * 512; }
    else return;
    int lane = f & 63, fr = f >> 6;
    int m = fr >> 3, ct = fr & 7;
    int col = ct * 16 + (lane & 15);
    int kb = m * 32 + ((lane >> 4) << 3);
    unsigned short v[8];
#pragma unroll
    for (int j = 0; j < 8; ++j) {
        int k = kb + j;
        v[j] = (k < Ksrc) ? f2b(W[k * 128 + col]) : (unsigned short)0;
    }
    *(short8*)(o + (size_t)f * 8) = *(short8*)v;
}

// --- xd = bf16(dis[v]*x[v]) padded to 96 cols; 4 u32 slots per thread -------
// slot s of row v = packbf(x[2s], x[2s+1]) * dis[v]; s>40 => 0 (pad)
__global__ __launch_bounds__(256) void k_xd(const float* __restrict__ x,
                                            const float* __restrict__ dis,
                                            unsigned int* __restrict__ xd, int n) {
    int tid = blockIdx.x * blockDim.x + threadIdx.x;
    if (tid >= n * 12) return;
    int v = tid / 12;
    int j = tid - v * 12;  // 0..11, covers slots 4j..4j+3
    float dv = dis[v];
    const float* xv = x + (size_t)v * 82;
    int s0 = 4 * j;
    // 4 independent guarded float2 loads (8B-aligned: rows are 328B)
    float2 t0 = (s0 + 0 <= 40) ? *(const float2*)(xv + 2 * (s0 + 0)) : make_float2(0.f, 0.f);
    float2 t1 = (s0 + 1 <= 40) ? *(const float2*)(xv + 2 * (s0 + 1)) : make_float2(0.f, 0.f);
    float2 t2 = (s0 + 2 <= 40) ? *(const float2*)(xv + 2 * (s0 + 2)) : make_float2(0.f, 0.f);
    float2 t3 = (s0 + 3 <= 40) ? *(const float2*)(xv + 2 * (s0 + 3)) : make_float2(0.f, 0.f);
    uint4 o;
    o.x = packbf(dv * t0.x, dv * t0.y);
    o.y = packbf(dv * t1.x, dv * t1.y);
    o.z = packbf(dv * t2.x, dv * t2.y);
    o.w = packbf(dv * t3.x, dv * t3.y);
    ((uint4*)(xd + (size_t)v * 48))[j] = o;  // 16B-aligned (192B rows)
}

// --- fused GCN layer, single-wave block (16 rows, no barrier) ---------------
// Input rows: RU = KS*16 u32 (2 bf16 each), dis-prescaled by producer.
// agg[v] = dis[v] * ( in[v] + sum_{u->v} in[u] );  out = relu(agg @ W + b)
// SCALE: out *= dis[row] (pre-scale for next layer). GATE: fused gate dot.
template <int KS, bool SCALE, bool GATE>
__global__ __launch_bounds__(64, 8) void k_fused(
    const unsigned int* __restrict__ hd, const float* __restrict__ dis,
    const int* __restrict__ rowstart, const int* __restrict__ csr,
    const unsigned short* __restrict__ Wp, const float* __restrict__ bias,
    unsigned short* __restrict__ out, const float* __restrict__ gw,
    const float* __restrict__ gb, float* __restrict__ gate, int n) {
    constexpr int RU = KS * 16;  // u32 per input row
    __shared__ unsigned int As[16 * 64];  // 16 rows x 256B (zero-padded), swizzled
    int lane = threadIdx.x & 63;
    int tile = blockIdx.x * 16;
    const bool act = (RU == 64) ? true : (lane < RU);
    const int li = act ? lane : 0;

    // ---- phase 1: gather 16 rows as 4 buckets of 4 (8-edge ILP) ----
    for (int g = 0; g < 4; ++g) {
        int r = g * 4;
        int v0 = tile + r;
        unsigned int* dst0 = &As[(r + 0) * 64 + (lane ^ (((r + 0) & 7) << 2))];
        unsigned int* dst1 = &As[(r + 1) * 64 + (lane ^ (((r + 1) & 7) << 2))];
        unsigned int* dst2 = &As[(r + 2) * 64 + (lane ^ (((r + 2) & 7) << 2))];
        unsigned int* dst3 = &As[(r + 3) * 64 + (lane ^ (((r + 3) & 7) << 2))];
        if (v0 >= n) {
            *dst0 = 0u; *dst1 = 0u; *dst2 = 0u; *dst3 = 0u;
            continue;
        }
        int nv = n - v0;
        if (nv > 4) nv = 4;
        int e0 = rowstart[v0];
        int eE = rowstart[v0 + nv];
        int b1 = (nv > 1) ? rowstart[v0 + 1] : eE;
        int b2 = (nv > 2) ? rowstart[v0 + 2] : eE;
        int b3 = (nv > 3) ? rowstart[v0 + 3] : eE;

        unsigned int s0 = hd[(size_t)v0 * RU + li];
        unsigned int s1 = (nv > 1) ? hd[(size_t)(v0 + 1) * RU + li] : 0u;
        unsigned int s2 = (nv > 2) ? hd[(size_t)(v0 + 2) * RU + li] : 0u;
        unsigned int s3 = (nv > 3) ? hd[(size_t)(v0 + 3) * RU + li] : 0u;
        float a0x = b2f(s0 << 16), a0y = b2f(s0 & 0xffff0000u);
        float a1x = b2f(s1 << 16), a1y = b2f(s1 & 0xffff0000u);
        float a2x = b2f(s2 << 16), a2y = b2f(s2 & 0xffff0000u);
        float a3x = b2f(s3 << 16), a3y = b2f(s3 & 0xffff0000u);

        for (int e = e0; e < eE; e += 8) {
            int rem = eE - e;
            int i1 = (rem > 1) ? e + 1 : e;
            int i2 = (rem > 2) ? e + 2 : e;
            int i3 = (rem > 3) ? e + 3 : e;
            int i4 = (rem > 4) ? e + 4 : e;
            int i5 = (rem > 5) ? e + 5 : e;
            int i6 = (rem > 6) ? e + 6 : e;
            int i7 = (rem > 7) ? e + 7 : e;
            int u0 = csr[e],  u1 = csr[i1], u2 = csr[i2], u3 = csr[i3];
            int u4 = csr[i4], u5 = csr[i5], u6 = csr[i6], u7 = csr[i7];
            unsigned int r0v = hd[(size_t)u0 * RU + li];
            unsigned int r1v = hd[(size_t)u1 * RU + li];
            unsigned int r2v = hd[(size_t)u2 * RU + li];
            unsigned int r3v = hd[(size_t)u3 * RU + li];
            unsigned int r4v = hd[(size_t)u4 * RU + li];
            unsigned int r5v = hd[(size_t)u5 * RU + li];
            unsigned int r6v = hd[(size_t)u6 * RU + li];
            unsigned int r7v = hd[(size_t)u7 * RU + li];
#define ACC(rv, ei)                                                     \
            {                                                           \
                float fx = b2f((rv) << 16), fy = b2f((rv) & 0xffff0000u); \
                if ((ei) < b1) { a0x += fx; a0y += fy; }                \
                else if ((ei) < b2) { a1x += fx; a1y += fy; }           \
                else if ((ei) < b3) { a2x += fx; a2y += fy; }           \
                else { a3x += fx; a3y += fy; }                          \
            }
            ACC(r0v, e)
            if (rem > 1) ACC(r1v, e + 1)
            if (rem > 2) ACC(r2v, e + 2)
            if (rem > 3) ACC(r3v, e + 3)
            if (rem > 4) ACC(r4v, e + 4)
            if (rem > 5) ACC(r5v, e + 5)
            if (rem > 6) ACC(r6v, e + 6)
            if (rem > 7) ACC(r7v, e + 7)
#undef ACC
        }

        float d0 = dis[v0];
        float d1 = (nv > 1) ? dis[v0 + 1] : 0.f;
        float d2 = (nv > 2) ? dis[v0 + 2] : 0.f;
        float d3 = (nv > 3) ? dis[v0 + 3] : 0.f;
        *dst0 = act ? packbf(d0 * a0x, d0 * a0y) : 0u;
        *dst1 = (act && nv > 1) ? packbf(d1 * a1x, d1 * a1y) : 0u;
        *dst2 = (act && nv > 2) ? packbf(d2 * a2x, d2 * a2y) : 0u;
        *dst3 = (act && nv > 3) ? packbf(d3 * a3x, d3 * a3y) : 0u;
    }
    // single wave: LDS writes visible after s_waitcnt; no barrier needed

    // ---- phase 2: MFMA on the 16-row tile ----
    int r0 = lane & 15, ch = lane >> 4;
    const unsigned int* arow = &As[r0 << 6];
    f32x4 acc[8];
#pragma unroll
    for (int ct = 0; ct < 8; ++ct) acc[ct] = (f32x4){0.f, 0.f, 0.f, 0.f};
#pragma unroll
    for (int m = 0; m < KS; ++m) {
        int slot = (ch + 4 * m) ^ (r0 & 7);
        short8 a = *(const short8*)(arow + slot * 4);
        const short8* wf = (const short8*)Wp + ((size_t)(m * 8) * 64 + lane);
#pragma unroll
        for (int ct = 0; ct < 8; ++ct) {
            short8 b = wf[ct * 64];
            acc[ct] = __builtin_amdgcn_mfma_f32_16x16x32_bf16(a, b, acc[ct], 0, 0, 0);
        }
    }

    // ---- epilogue ----
    float bb[8], gwv[8];
#pragma unroll
    for (int ct = 0; ct < 8; ++ct) {
        bb[ct] = bias[ct * 16 + r0];
        if (GATE) gwv[ct] = gw[ct * 16 + r0];
    }
    float gbv = GATE ? gb[0] : 0.f;
    int rbase = tile + (ch << 2);
#pragma unroll
    for (int reg = 0; reg < 4; ++reg) {
        int row = rbase + reg;
        bool ok = row < n;
        float dv = (SCALE && ok) ? dis[row] : 1.f;
        float gp = 0.f;
#pragma unroll
        for (int ct = 0; ct < 8; ++ct) {
            float o = fmaxf(acc[ct][reg] + bb[ct], 0.f);
            if (GATE) gp = fmaf(o, gwv[ct], gp);
            if (ok) out[(size_t)row * 128 + ct * 16 + r0] = f2b(SCALE ? o * dv : o);
        }
        if (GATE) {
            gp += __shfl_xor(gp, 1);
            gp += __shfl_xor(gp, 2);
            gp += __shfl_xor(gp, 4);
            gp += __shfl_xor(gp, 8);
            if (r0 == 0 && ok) gate[row] = gp + gbv;
        }
    }
}

// --- attention pooling: one wave per graph, inline bounds, ILP-4 sum --------
__global__ __launch_bounds__(256) void k_pool(const unsigned short* __restrict__ h,
                                              const float* __restrict__ gate,
                                              const int* __restrict__ batch,
                                              float* __restrict__ emb, int n, int B) {
    int wid = (blockIdx.x * blockDim.x + threadIdx.x) >> 6;
    int lane = threadIdx.x & 63;
    if (wid >= B) return;
    int bnd = 0;
    if (lane < 2) {
        int g = wid + lane;
        int lo = 0, hi = n;
        while (lo < hi) {
            int mid = (lo + hi) >> 1;
            if (batch[mid] < g) lo = mid + 1;
            else hi = mid;
        }
        bnd = lo;
    }
    int s = __shfl(bnd, 0), e2 = __shfl(bnd, 1);
    float* ev2 = emb + (size_t)wid * 128 + lane * 2;
    if (s >= e2) {
        ev2[0] = 0.f;
        ev2[1] = 0.f;
        return;
    }
    float m = -INFINITY;
    for (int v = s + lane; v < e2; v += 64) m = fmaxf(m, gate[v]);
#pragma unroll
    for (int off = 32; off; off >>= 1) m = fmaxf(m, __shfl_xor(m, off));
    float a0 = 0.f, a1 = 0.f, den = 0.f;
    const unsigned int* h32 = (const unsigned int*)h;
    int v = s;
    for (; v + 4 <= e2; v += 4) {
        float g0 = gate[v], g1 = gate[v + 1], g2 = gate[v + 2], g3 = gate[v + 3];
        unsigned int h0 = h32[(size_t)(v + 0) * 64 + lane];
        unsigned int h1 = h32[(size_t)(v + 1) * 64 + lane];
        unsigned int h2 = h32[(size_t)(v + 2) * 64 + lane];
        unsigned int h3 = h32[(size_t)(v + 3) * 64 + lane];
        float e0 = __expf(g0 - m), e1 = __expf(g1 - m);
        float e2v = __expf(g2 - m), e3 = __expf(g3 - m);
        den += (e0 + e1) + (e2v + e3);
        a0 = fmaf(e0, b2f(h0 << 16), a0);
        a1 = fmaf(e0, b2f(h0 & 0xffff0000u), a1);
        a0 = fmaf(e1, b2f(h1 << 16), a0);
        a1 = fmaf(e1, b2f(h1 & 0xffff0000u), a1);
        a0 = fmaf(e2v, b2f(h2 << 16), a0);
        a1 = fmaf(e2v, b2f(h2 & 0xffff0000u), a1);
        a0 = fmaf(e3, b2f(h3 << 16), a0);
        a1 = fmaf(e3, b2f(h3 & 0xffff0000u), a1);
    }
    for (; v < e2; ++v) {
        float ev = __expf(gate[v] - m);
        den += ev;
        unsigned int hv = h32[(size_t)v * 64 + lane];
        a0 = fmaf(ev, b2f(hv << 16), a0);
        a1 = fmaf(ev, b2f(hv & 0xffff0000u), a1);
    }
    float inv = 1.f / den;
    ev2[0] = a0 * inv;
    ev2[1] = a1 * inv;
}

// --- final projection: 32 graphs per block ----------------------------------
__global__ __launch_bounds__(256) void k_proj(const float* __restrict__ emb,
                                              const float* __restrict__ pw,
                                              const float* __restrict__ pb,
                                              float* __restrict__ out, int B) {
    __shared__ float es[32][128];
    int g0 = blockIdx.x * 32;
    int t = threadIdx.x;
    for (int i = t; i < 1024; i += 256) {
        int g = g0 + (i >> 5);
        float4 val = (g < B) ? ((const float4*)emb)[(size_t)g * 32 + (i & 31)]
                             : make_float4(0.f, 0.f, 0.f, 0.f);
        *(float4*)&es[i >> 5][(i & 31) * 4] = val;
    }
    __syncthreads();
    float acc[32];
#pragma unroll
    for (int i = 0; i < 32; ++i) acc[i] = 0.f;
    for (int k = 0; k < 128; ++k) {
        float wv = pw[k * 256 + t];
#pragma unroll
        for (int i = 0; i < 32; ++i) acc[i] = fmaf(es[i][k], wv, acc[i]);
    }
    float b = pb[t];
#pragma unroll
    for (int i = 0; i < 32; ++i) {
        int g = g0 + i;
        if (g < B) out[(size_t)g * 256 + t] = acc[i] + b;
    }
}

// ---------------------------------------------------------------------------
extern "C" void kernel_launch(void* const* d_in, const int* in_sizes, int n_in,
                              void* d_out, int out_size, void* d_ws, size_t ws_size,
                              hipStream_t stream) {
    const float* x = (const float*)d_in[0];
    const int* ei = (const int*)d_in[1];
    const int* batch = (const int*)d_in[2];
    const float* W0 = (const float*)d_in[3];
    const float* b0 = (const float*)d_in[4];
    const float* W1 = (const float*)d_in[5];
    const float* b1 = (const float*)d_in[6];
    const float* W2 = (const float*)d_in[7];
    const float* b2 = (const float*)d_in[8];
    const float* gw = (const float*)d_in[9];
    const float* gb = (const float*)d_in[10];
    const float* pw = (const float*)d_in[11];
    const float* pb = (const float*)d_in[12];
    float* out = (float*)d_out;

    const int N = in_sizes[2];
    const int E = in_sizes[1] / 2;
    const int B = out_size / 256;
    (void)n_in;

    const int* esrc = ei;
    const int* edst = ei + E;

    char* p = (char*)d_ws;
    auto carve = [&](size_t bytes) {
        char* r = p;
        p += (bytes + 255) & ~(size_t)255;
        return r;
    };
    unsigned int* xd = (unsigned int*)carve((size_t)N * 48 * 4);
    unsigned int* hA = (unsigned int*)carve((size_t)N * 64 * 4);
    unsigned int* hB = (unsigned int*)carve((size_t)N * 64 * 4);
    float* emb = (float*)carve((size_t)B * 128 * 4);
    int* csr_src = (int*)carve((size_t)E * 4);
    float* dis = (float*)carve((size_t)N * 4);
    int* cnt = (int*)carve((size_t)2 * N * 4);  // cnt + cur0 (one memset)
    int* cur0 = cnt + N;
    int* rowstart = (int*)carve((size_t)(N + 1) * 4);
    float* gate = (float*)carve((size_t)N * 4);
    int* bsum = (int*)carve((size_t)4096 * 4);
    unsigned short* wp0 = (unsigned short*)carve((size_t)3 * 512 * 8 * 2);
    unsigned short* wp1 = (unsigned short*)carve((size_t)4 * 512 * 8 * 2);
    unsigned short* wp2 = (unsigned short*)carve((size_t)4 * 512 * 8 * 2);
    if ((size_t)(p - (char*)d_ws) > ws_size) return;

    const int nb = (N + 2047) / 2048;  // 245 (<= 256 required by k_scan3)

    hipMemsetAsync(cnt, 0, (size_t)2 * N * 4, stream);
    k_count<<<(E + 255) / 256, 256, 0, stream>>>(edst, cnt, E);
    k_scan1<<<nb, 256, 0, stream>>>(cnt, rowstart + 1, bsum, dis, N);
    k_scan3<<<nb, 256, 0, stream>>>(rowstart, bsum, N);
    k_fill<<<(E + 255) / 256, 256, 0, stream>>>(esrc, edst, rowstart, cur0, csr_src, E);
    k_cvtw3<<<22, 256, 0, stream>>>(W0, W1, W2, wp0, wp1, wp2);
    k_xd<<<(N * 12 + 255) / 256, 256, 0, stream>>>(x, dis, xd, N);

    const int fb = (N + 15) / 16;  // single-wave blocks, 16 rows each

    // layer 0: xd -> hA (bf16, dis-prescaled)
    k_fused<3, true, false><<<fb, 64, 0, stream>>>(
        xd, dis, rowstart, csr_src, wp0, b0, (unsigned short*)hA,
        nullptr, nullptr, nullptr, N);
    // layer 1: hA -> hB (bf16, dis-prescaled)
    k_fused<4, true, false><<<fb, 64, 0, stream>>>(
        hA, dis, rowstart, csr_src, wp1, b1, (unsigned short*)hB,
        nullptr, nullptr, nullptr, N);
    // layer 2: hB -> hA (unscaled) + gate
    k_fused<4, false, true><<<fb, 64, 0, stream>>>(
        hB, dis, rowstart, csr_src, wp2, b2, (unsigned short*)hA,
        gw, gb, gate, N);

    // pooling + projection
    k_pool<<<(B + 3) / 4, 256, 0, stream>>>((const unsigned short*)hA, gate, batch,
                                            emb, N, B);
    k_proj<<<(B + 31) / 32, 256, 0, stream>>>(emb, pw, pb, out, B);
}